// Round 12
// baseline (404.603 us; speedup 1.0000x reference)
//
#include <hip/hip_runtime.h>
#include <hip/hip_bf16.h>

#define T_    16
#define C_    64
#define H_    48
#define W_    48
#define HW_   2304
#define THW_  36864
#define CTHW_ 2359296
#define H2_   24
#define W2_   24
#define SD_   576
#define RC_   4
#define SDT_  72    // bf16 LDS tile row stride in shorts (144 B, 16B-multiple)

typedef short short8 __attribute__((ext_vector_type(8)));
typedef float f32x4 __attribute__((ext_vector_type(4)));

__device__ __forceinline__ float sigm(float v) { return 1.f / (1.f + __expf(-v)); }
__device__ __forceinline__ unsigned short f2bf(float v) {
    __hip_bfloat16 h = __float2bfloat16(v);
    union { __hip_bfloat16 h; unsigned short u; } cv; cv.h = h; return cv.u;
}
__device__ __forceinline__ float bf2f(unsigned short u) {
    return __uint_as_float((unsigned)u << 16);
}

// ---------------- k_pre: fused x2T GEMM + bf16 split of x + xd = w_down@x ----------------
__global__ __launch_bounds__(256) void k_pre(const float* __restrict__ x,
                                             const float* __restrict__ w,
                                             const float* __restrict__ w_down,
                                             float* __restrict__ x2T,
                                             unsigned short* __restrict__ xbh,
                                             unsigned short* __restrict__ xbl,
                                             float* __restrict__ xd) {
    int base = blockIdx.x * 64;
    __shared__ float wl[64 * 65];   // w_dc2 [o][c] padded
    __shared__ float xt[4096];      // [c][u]
    __shared__ float ld[64 * 65];   // [c][u] padded
    __shared__ float wd[256];
    int tid = threadIdx.x;
    for (int i = tid; i < 4096; i += 256) wl[(i >> 6) * 65 + (i & 63)] = w[i];
    for (int i = tid; i < 4096; i += 256) {
        float v = x[(size_t)(i >> 6) * THW_ + base + (i & 63)];
        xt[i] = v;
        ld[(i >> 6) * 65 + (i & 63)] = v;
    }
    if (tid < 256) wd[tid] = w_down[tid];
    __syncthreads();
    {
        int o_grp = tid >> 4, u_grp = tid & 15;
        float acc[4][4] = {};
        const float4* xt4 = (const float4*)xt;
        for (int c = 0; c < 64; ++c) {
            float xa[4];
            *(float4*)xa = xt4[c * 16 + u_grp];
            #pragma unroll
            for (int i = 0; i < 4; ++i) {
                float wv = wl[(o_grp * 4 + i) * 65 + c];
                #pragma unroll
                for (int g = 0; g < 4; ++g) acc[i][g] += wv * xa[g];
            }
        }
        #pragma unroll
        for (int g = 0; g < 4; ++g) {
            float4 v = make_float4(acc[0][g], acc[1][g], acc[2][g], acc[3][g]);
            *(float4*)&x2T[(size_t)(base + u_grp * 4 + g) * 64 + o_grp * 4] = v;
        }
    }
    {
        int r = tid >> 6, u = tid & 63;
        float a = 0.f;
        #pragma unroll 8
        for (int c = 0; c < 64; ++c) a += wd[r * 64 + c] * xt[c * 64 + u];
        xd[(size_t)r * THW_ + base + u] = a;
    }
    for (int i = tid; i < 4096; i += 256) {
        int u = i >> 6, c = i & 63;
        float v = ld[c * 65 + u];
        unsigned short h = f2bf(v);
        xbh[(size_t)(base + u) * 64 + c] = h;
        xbl[(size_t)(base + u) * 64 + c] = f2bf(v - bf2f(h));
    }
}

// ---------------- k_off (verbatim) ----------------
__global__ __launch_bounds__(256) void k_off(const float* __restrict__ x,
                                             const float* __restrict__ x2T,
                                             const float* __restrict__ w_l,
                                             const float* __restrict__ b_l,
                                             const float* __restrict__ w_r,
                                             const float* __restrict__ b_r,
                                             float* __restrict__ off) {
    __shared__ float wlds[2304];
    int tid = threadIdx.x;
    for (int i = tid; i < 2304; i += 256) wlds[i] = (i < 1152) ? w_l[i] : w_r[i - 1152];
    __syncthreads();
    int wg = blockIdx.x * 4 + (tid >> 6);
    int lane = tid & 63;
    int j = wg % 24, i = (wg / 24) % 24, t = (wg / 576) % 16, side = wg / 9216;
    int ts = (side == 0) ? min(t + 1, T_ - 1) : max(t - 1, 0);
    const float* wp = wlds + side * 1152;
    const float* xl = x + (size_t)lane * THW_ + t * HW_;
    const float* x2l = x2T + (size_t)ts * HW_ * 64 + lane;
    float a0 = 0.f, a1 = 0.f;
    for (int ki = 0; ki < 3; ++ki) {
        int hh = 2 * i - 1 + ki;
        if (hh < 0 || hh >= H_) continue;
        for (int kj = 0; kj < 3; ++kj) {
            int ww = 2 * j - 1 + kj;
            if (ww < 0 || ww >= W_) continue;
            int pos = hh * W_ + ww;
            float s = xl[pos] + x2l[(size_t)pos * 64];
            int tap = ki * 3 + kj;
            a0 += s * wp[lane * 9 + tap];
            a1 += s * wp[576 + lane * 9 + tap];
        }
    }
    #pragma unroll
    for (int m = 32; m >= 1; m >>= 1) {
        a0 += __shfl_xor(a0, m);
        a1 += __shfl_xor(a1, m);
    }
    if (lane == 0) {
        const float* bb = (side == 0) ? b_l : b_r;
        int ob = (side * 16 + t) * 1152 + i * 24 + j;
        off[ob] = a0 + bb[0];
        off[ob + 576] = a1 + bb[1];
    }
}

// ---------------- k_gs (verbatim) ----------------
__global__ __launch_bounds__(256) void k_gs(const float* __restrict__ x2T,
                                            const float* __restrict__ off,
                                            unsigned short* __restrict__ pch,
                                            unsigned short* __restrict__ pcl) {
    int wg = blockIdx.x * 4 + (threadIdx.x >> 6);
    int lane = threadIdx.x & 63;
    int sd = wg % 576;
    int t = (wg / 576) % 16;
    int side = wg / 9216;
    int d = sd % W2_, s = sd / W2_;
    const float* offp = off + (side * 16 + t) * 1152;
    float v0 = 2.f * (float)d + offp[sd];
    float v1 = 2.f * (float)s + offp[576 + sd];
    float xf = 48.f * v0 / 23.f - 0.5f;
    float yf = 48.f * v1 / 23.f - 0.5f;
    float x0 = floorf(xf), y0 = floorf(yf);
    int ix0 = (int)x0, iy0 = (int)y0;
    float fx = xf - x0, fy = yf - y0;
    float w00 = (1.f - fx) * (1.f - fy), w10 = fx * (1.f - fy);
    float w01 = (1.f - fx) * fy,         w11 = fx * fy;
    bool vx0 = (ix0 >= 0 && ix0 < W_), vx1 = (ix0 + 1 >= 0 && ix0 + 1 < W_);
    bool vy0 = (iy0 >= 0 && iy0 < H_), vy1 = (iy0 + 1 >= 0 && iy0 + 1 < H_);
    int cx0 = min(max(ix0, 0), W_ - 1), cx1 = min(max(ix0 + 1, 0), W_ - 1);
    int cy0 = min(max(iy0, 0), H_ - 1), cy1 = min(max(iy0 + 1, 0), H_ - 1);
    float m00 = (vx0 && vy0) ? w00 : 0.f;
    float m10 = (vx1 && vy0) ? w10 : 0.f;
    float m01 = (vx0 && vy1) ? w01 : 0.f;
    float m11 = (vx1 && vy1) ? w11 : 0.f;
    int ts = (side == 0) ? min(t + 1, T_ - 1) : max(t - 1, 0);
    const float* img = x2T + (size_t)ts * HW_ * 64;
    float val = m00 * img[(size_t)(cy0 * W_ + cx0) * 64 + lane]
              + m10 * img[(size_t)(cy0 * W_ + cx1) * 64 + lane]
              + m01 * img[(size_t)(cy1 * W_ + cx0) * 64 + lane]
              + m11 * img[(size_t)(cy1 * W_ + cx1) * 64 + lane];
    size_t idx = ((size_t)(side * 16 + t) * 576 + sd) * 64 + lane;
    unsigned short h = f2bf(val);
    pch[idx] = h;
    pcl[idx] = f2bf(val - bf2f(h));
}

// ---------------- k_tr (verbatim) ----------------
__global__ __launch_bounds__(256) void k_tr(const unsigned short* __restrict__ pch,
                                            unsigned short* __restrict__ partb) {
    int st = blockIdx.x / 9;
    int sdt = blockIdx.x % 9;
    __shared__ unsigned short ld[64 * 68];
    int tid = threadIdx.x;
    const unsigned short* src = pch + ((size_t)st * 576 + sdt * 64) * 64;
    for (int i = tid; i < 4096; i += 256) ld[(i >> 6) * 68 + (i & 63)] = src[i];
    __syncthreads();
    unsigned short* dst = partb + (size_t)st * 64 * 576 + sdt * 64;
    for (int i = tid; i < 4096; i += 256) {
        int c = i >> 6, sdl = i & 63;
        dst[(size_t)c * 576 + sdl] = ld[sdl * 68 + c];
    }
}

// ---------------- k_stats: LDS-free MFMA split-bf16 aff GEMM + stats, both sides -------
// grid: t(16) x hw-tile(36); all fragments loaded directly from global (MFMA-layout match)
__global__ __launch_bounds__(256) void k_stats(const unsigned short* __restrict__ xbh,
                                               const unsigned short* __restrict__ xbl,
                                               const unsigned short* __restrict__ pch,
                                               const unsigned short* __restrict__ pcl,
                                               float* __restrict__ stats) {
    int bid = blockIdx.x;
    int t = bid / 36, hwt = bid % 36;
    int base = t * HW_ + hwt * 64;
    int tid = threadIdx.x;
    int lane = tid & 63, wv = tid >> 6;
    int quad = lane >> 4, l15 = lane & 15;
    int m0 = wv * 16;
    const unsigned short* xrh = xbh + (size_t)(base + m0 + l15) * 64;
    const unsigned short* xrl = xbl + (size_t)(base + m0 + l15) * 64;
    short8 ah0 = *(const short8*)&xrh[quad * 8];
    short8 ah1 = *(const short8*)&xrh[32 + quad * 8];
    short8 al0 = *(const short8*)&xrl[quad * 8];
    short8 al1 = *(const short8*)&xrl[32 + quad * 8];
    for (int side = 0; side < 2; ++side) {
        const unsigned short* ph = pch + (size_t)(side * 16 + t) * 576 * 64;
        const unsigned short* pl = pcl + (size_t)(side * 16 + t) * 576 * 64;
        float sum[4] = {0,0,0,0}, sq[4] = {0,0,0,0}, mx[4] = {-1e30f,-1e30f,-1e30f,-1e30f};
        for (int kt = 0; kt < 9; ++kt) {
            #pragma unroll
            for (int tile = 0; tile < 4; ++tile) {
                const unsigned short* prh = ph + (size_t)(kt * 64 + tile * 16 + l15) * 64;
                const unsigned short* prl = pl + (size_t)(kt * 64 + tile * 16 + l15) * 64;
                short8 bh0 = *(const short8*)&prh[quad * 8];
                short8 bh1 = *(const short8*)&prh[32 + quad * 8];
                short8 bl0 = *(const short8*)&prl[quad * 8];
                short8 bl1 = *(const short8*)&prl[32 + quad * 8];
                f32x4 dacc = {0.f, 0.f, 0.f, 0.f};
                dacc = __builtin_amdgcn_mfma_f32_16x16x32_bf16(ah0, bh0, dacc, 0, 0, 0);
                dacc = __builtin_amdgcn_mfma_f32_16x16x32_bf16(ah1, bh1, dacc, 0, 0, 0);
                dacc = __builtin_amdgcn_mfma_f32_16x16x32_bf16(ah0, bl0, dacc, 0, 0, 0);
                dacc = __builtin_amdgcn_mfma_f32_16x16x32_bf16(ah1, bl1, dacc, 0, 0, 0);
                dacc = __builtin_amdgcn_mfma_f32_16x16x32_bf16(al0, bh0, dacc, 0, 0, 0);
                dacc = __builtin_amdgcn_mfma_f32_16x16x32_bf16(al1, bh1, dacc, 0, 0, 0);
                #pragma unroll
                for (int r = 0; r < 4; ++r) {
                    float v = dacc[r];
                    sum[r] += v; sq[r] += v * v; mx[r] = fmaxf(mx[r], v);
                }
            }
        }
        #pragma unroll
        for (int m = 1; m < 16; m <<= 1)
            #pragma unroll
            for (int r = 0; r < 4; ++r) {
                sum[r] += __shfl_xor(sum[r], m);
                sq[r]  += __shfl_xor(sq[r], m);
                mx[r]   = fmaxf(mx[r], __shfl_xor(mx[r], m));
            }
        if (l15 == 0) {
            #pragma unroll
            for (int r = 0; r < 4; ++r) {
                int thw = base + m0 + quad * 4 + r;
                stats[(side * 3 + 0) * THW_ + thw] = sum[r] * (1.f / 576.f);
                stats[(side * 3 + 1) * THW_ + thw] = mx[r];
                stats[(side * 3 + 2) * THW_ + thw] = (sq[r] - sum[r] * sum[r] * (1.f / 576.f)) * (1.f / 575.f);
            }
        }
    }
}

// ---------------- k_attn (verbatim) ----------------
__global__ void k_attn(const float* __restrict__ stats, const float* __restrict__ ca_w1,
                       const float* __restrict__ ca_w2, float* __restrict__ yb) {
    int idx = blockIdx.x * 256 + threadIdx.x;
    if (idx >= 2 * THW_) return;
    int side = idx / THW_, thw = idx % THW_;
    int w = thw % W_, h = (thw / W_) % H_, t = thw / HW_;
    const float* avg = stats + (side * 3 + 0) * THW_ + t * HW_;
    const float* mxp = stats + (side * 3 + 1) * THW_ + t * HW_;
    const float* var = stats + (side * 3 + 2) * THW_ + t * HW_;
    float acc = 0.f;
    for (int ki = 0; ki < 3; ++ki) {
        int hh = h - 1 + ki;
        if (hh < 0 || hh >= H_) continue;
        for (int kj = 0; kj < 3; ++kj) {
            int ww = w - 1 + kj;
            if (ww < 0 || ww >= W_) continue;
            int p = hh * W_ + ww;
            int kk = ki * 3 + kj;
            acc += ca_w1[kk] * avg[p] + ca_w1[9 + kk] * mxp[p] + ca_w2[kk] * var[p];
        }
    }
    yb[idx] = sigm(acc);
}

// ---------------- k_agg (verbatim) ----------------
__global__ void k_agg(const float* __restrict__ xd,
                      const float* __restrict__ w1, const float* __restrict__ b1,
                      const float* __restrict__ w2, const float* __restrict__ b2,
                      const float* __restrict__ w3, const float* __restrict__ b3,
                      const float* __restrict__ wts, float* __restrict__ agg0) {
    int idx = blockIdx.x * 256 + threadIdx.x;
    if (idx >= RC_ * THW_) return;
    int w = idx % W_;
    int h = (idx / W_) % H_;
    int t = (idx / HW_) % T_;
    int r = idx / THW_;
    const float* xr = xd + r * THW_;
    const float* wk_arr[3] = {w1, w2, w3};
    const float* bs_arr[3] = {b1, b2, b3};
    float tot = 0.f;
    for (int m = 0; m < 3; ++m) {
        int dil = m + 1;
        float acc = bs_arr[m][r];
        const float* wk = wk_arr[m] + r * 81;
        for (int kt = 0; kt < 9; ++kt) {
            int tt = t - 4 + kt;
            if (tt < 0 || tt >= T_) continue;
            for (int kh = 0; kh < 3; ++kh) {
                int hh = h + (kh - 1) * dil;
                if (hh < 0 || hh >= H_) continue;
                for (int kw = 0; kw < 3; ++kw) {
                    int wwp = w + (kw - 1) * dil;
                    if (wwp < 0 || wwp >= W_) continue;
                    acc += xr[tt * HW_ + hh * W_ + wwp] * wk[kt * 9 + kh * 3 + kw];
                }
            }
        }
        tot += acc * wts[m];
    }
    agg0[idx] = tot;
}

// ---------------- k_final: direct-global fragments, LDS only for wt; 2 syncs/kt --------
// grid: t(16) x hw-tile(36)
__global__ __launch_bounds__(256) void k_final(const unsigned short* __restrict__ xbh,
                                               const unsigned short* __restrict__ xbl,
                                               const unsigned short* __restrict__ pch,
                                               const unsigned short* __restrict__ pcl,
                                               const unsigned short* __restrict__ partb,
                                               const float* __restrict__ yb,
                                               const float* __restrict__ weights2,
                                               const float* __restrict__ agg0,
                                               const float* __restrict__ w_back,
                                               float* __restrict__ out) {
    int bid = blockIdx.x;
    int t = bid / 36, hwt = bid % 36;
    int base = t * HW_ + hwt * 64;
    __shared__ __attribute__((aligned(16))) unsigned short wt[64 * SDT_];
    int tid = threadIdx.x;
    int lane = tid & 63, wv = tid >> 6;
    int quad = lane >> 4, l15 = lane & 15;
    int m0 = wv * 16;
    const unsigned short* xrh = xbh + (size_t)(base + m0 + l15) * 64;
    const unsigned short* xrl = xbl + (size_t)(base + m0 + l15) * 64;
    short8 ah0 = *(const short8*)&xrh[quad * 8];
    short8 ah1 = *(const short8*)&xrh[32 + quad * 8];
    short8 al0 = *(const short8*)&xrl[quad * 8];
    short8 al1 = *(const short8*)&xrl[32 + quad * 8];
    float yv2[2][4];
    #pragma unroll
    for (int s = 0; s < 2; ++s)
        #pragma unroll
        for (int r = 0; r < 4; ++r) yv2[s][r] = yb[s * THW_ + base + m0 + quad * 4 + r];
    f32x4 acc2[2][4] = {};
    for (int side = 0; side < 2; ++side) {
        const unsigned short* ph = pch + (size_t)(side * 16 + t) * 576 * 64;
        const unsigned short* pl = pcl + (size_t)(side * 16 + t) * 576 * 64;
        const unsigned short* pb = partb + (size_t)(side * 16 + t) * 64 * 576;
        for (int kt = 0; kt < 9; ++kt) {
            // phase A: aff tiles (split bf16, direct global B-frags) -> weight values
            unsigned short wtv[4][4];
            #pragma unroll
            for (int tile = 0; tile < 4; ++tile) {
                const unsigned short* prh = ph + (size_t)(kt * 64 + tile * 16 + l15) * 64;
                const unsigned short* prl = pl + (size_t)(kt * 64 + tile * 16 + l15) * 64;
                short8 bh0 = *(const short8*)&prh[quad * 8];
                short8 bh1 = *(const short8*)&prh[32 + quad * 8];
                short8 bl0 = *(const short8*)&prl[quad * 8];
                short8 bl1 = *(const short8*)&prl[32 + quad * 8];
                f32x4 dacc = {0.f, 0.f, 0.f, 0.f};
                dacc = __builtin_amdgcn_mfma_f32_16x16x32_bf16(ah0, bh0, dacc, 0, 0, 0);
                dacc = __builtin_amdgcn_mfma_f32_16x16x32_bf16(ah1, bh1, dacc, 0, 0, 0);
                dacc = __builtin_amdgcn_mfma_f32_16x16x32_bf16(ah0, bl0, dacc, 0, 0, 0);
                dacc = __builtin_amdgcn_mfma_f32_16x16x32_bf16(ah1, bl1, dacc, 0, 0, 0);
                dacc = __builtin_amdgcn_mfma_f32_16x16x32_bf16(al0, bh0, dacc, 0, 0, 0);
                dacc = __builtin_amdgcn_mfma_f32_16x16x32_bf16(al1, bh1, dacc, 0, 0, 0);
                #pragma unroll
                for (int r = 0; r < 4; ++r)
                    wtv[tile][r] = f2bf(sigm(dacc[r] * yv2[side][r]) - 0.5f);
            }
            __syncthreads();   // WAR: previous phase B finished reading wt
            #pragma unroll
            for (int tile = 0; tile < 4; ++tile)
                #pragma unroll
                for (int r = 0; r < 4; ++r)
                    wt[(m0 + quad * 4 + r) * SDT_ + tile * 16 + l15] = wtv[tile][r];
            __syncthreads();   // wt visible
            // phase B: P (direct global A-frag) x wt^T
            const unsigned short* pbr = pb + (size_t)(m0 + l15) * 576 + kt * 64;
            short8 pA0 = *(const short8*)&pbr[quad * 8];
            short8 pA1 = *(const short8*)&pbr[32 + quad * 8];
            #pragma unroll
            for (int tile = 0; tile < 4; ++tile) {
                short8 wb0 = *(const short8*)&wt[(tile * 16 + l15) * SDT_ + quad * 8];
                short8 wb1 = *(const short8*)&wt[(tile * 16 + l15) * SDT_ + 32 + quad * 8];
                acc2[side][tile] = __builtin_amdgcn_mfma_f32_16x16x32_bf16(pA0, wb0, acc2[side][tile], 0, 0, 0);
                acc2[side][tile] = __builtin_amdgcn_mfma_f32_16x16x32_bf16(pA1, wb1, acc2[side][tile], 0, 0, 0);
            }
        }
    }
    float w20 = weights2[0], w21 = weights2[1];
    #pragma unroll
    for (int tile = 0; tile < 4; ++tile) {
        int thw = base + tile * 16 + l15;
        #pragma unroll
        for (int r = 0; r < 4; ++r) {
            int c = m0 + quad * 4 + r;
            float a = 0.f;
            #pragma unroll
            for (int rr = 0; rr < RC_; ++rr) a += w_back[c * RC_ + rr] * agg0[rr * THW_ + thw];
            out[(size_t)c * THW_ + thw] =
                (acc2[0][tile][r] * w20 + acc2[1][tile][r] * w21) * (sigm(a) - 0.5f);
        }
    }
}

extern "C" void kernel_launch(void* const* d_in, const int* in_sizes, int n_in,
                              void* d_out, int out_size, void* d_ws, size_t ws_size,
                              hipStream_t stream) {
    const float* x       = (const float*)d_in[0];
    const float* w_dc2   = (const float*)d_in[1];
    const float* w_ofs_l = (const float*)d_in[2];
    const float* b_ofs_l = (const float*)d_in[3];
    const float* w_ofs_r = (const float*)d_in[4];
    const float* b_ofs_r = (const float*)d_in[5];
    const float* ca_w1   = (const float*)d_in[6];
    const float* ca_w2   = (const float*)d_in[7];
    const float* w_down  = (const float*)d_in[8];
    const float* sa1_w   = (const float*)d_in[9];
    const float* sa1_b   = (const float*)d_in[10];
    const float* sa2_w   = (const float*)d_in[11];
    const float* sa2_b   = (const float*)d_in[12];
    const float* sa3_w   = (const float*)d_in[13];
    const float* sa3_b   = (const float*)d_in[14];
    const float* weights = (const float*)d_in[15];
    const float* weights2= (const float*)d_in[16];
    const float* w_back  = (const float*)d_in[17];
    float* out = (float*)d_out;

    // workspace ~24.3 MB (identical layout to round 11)
    float* ws    = (float*)d_ws;
    float* x2T   = ws;                               // CTHW_ f32
    float* stats = x2T;                              // overlay: 221,184 f32
    float* yb    = stats + 2 * 3 * THW_;             // 73,728
    float* agg0  = yb + 2 * THW_;                    // 147,456
    unsigned short* partb = (unsigned short*)(agg0 + RC_ * THW_);  // 1,179,648 u16
    float* off   = ws + CTHW_;                       // 36,864 f32
    unsigned short* xbh = (unsigned short*)(off + 2 * T_ * 2 * SD_);  // CTHW_ u16
    unsigned short* xbl = xbh + CTHW_;                                // CTHW_ u16
    unsigned short* pch = xbl + CTHW_;               // 1,179,648 u16
    unsigned short* pcl = pch + 2 * 16 * 576 * 64;   // 1,179,648 u16
    float* xd    = (float*)(pcl + 2 * 16 * 576 * 64); // 147,456 f32

    k_pre<<<THW_ / 64, 256, 0, stream>>>(x, w_dc2, w_down, x2T, xbh, xbl, xd);
    k_off<<<(2 * 16 * 576) / 4, 256, 0, stream>>>(x, x2T, w_ofs_l, b_ofs_l,
                                                  w_ofs_r, b_ofs_r, off);
    k_gs<<<(2 * 16 * 576) / 4, 256, 0, stream>>>(x2T, off, pch, pcl);
    k_tr<<<32 * 9, 256, 0, stream>>>(pch, partb);
    k_stats<<<16 * 36, 256, 0, stream>>>(xbh, xbl, pch, pcl, stats);
    k_attn<<<(2 * THW_) / 256, 256, 0, stream>>>(stats, ca_w1, ca_w2, yb);
    k_agg<<<(RC_ * THW_) / 256, 256, 0, stream>>>(xd, sa1_w, sa1_b, sa2_w, sa2_b,
                                                  sa3_w, sa3_b, weights, agg0);
    k_final<<<16 * 36, 256, 0, stream>>>(xbh, xbl, pch, pcl, partb, yb, weights2,
                                         agg0, w_back, out);
}

// Round 13
// 284.820 us; speedup vs baseline: 1.4206x; 1.4206x over previous
//
#include <hip/hip_runtime.h>
#include <hip/hip_bf16.h>

#define T_    16
#define C_    64
#define H_    48
#define W_    48
#define HW_   2304
#define THW_  36864
#define CTHW_ 2359296
#define H2_   24
#define W2_   24
#define SD_   576
#define RC_   4
#define SDT_  72    // bf16 LDS tile row stride in shorts (144 B, 16B-multiple)

typedef short short8 __attribute__((ext_vector_type(8)));
typedef float f32x4 __attribute__((ext_vector_type(4)));

__device__ __forceinline__ float sigm(float v) { return 1.f / (1.f + __expf(-v)); }
__device__ __forceinline__ unsigned short f2bf(float v) {
    __hip_bfloat16 h = __float2bfloat16(v);
    union { __hip_bfloat16 h; unsigned short u; } cv; cv.h = h; return cv.u;
}
__device__ __forceinline__ float bf2f(unsigned short u) {
    return __uint_as_float((unsigned)u << 16);
}

// ---------------- k_pre: fused x2T GEMM + bf16 split of x + xd = w_down@x ----------------
__global__ __launch_bounds__(256) void k_pre(const float* __restrict__ x,
                                             const float* __restrict__ w,
                                             const float* __restrict__ w_down,
                                             float* __restrict__ x2T,
                                             unsigned short* __restrict__ xbh,
                                             unsigned short* __restrict__ xbl,
                                             float* __restrict__ xd) {
    int base = blockIdx.x * 64;
    __shared__ float wl[64 * 65];
    __shared__ float xt[4096];
    __shared__ float ld[64 * 65];
    __shared__ float wd[256];
    int tid = threadIdx.x;
    for (int i = tid; i < 4096; i += 256) wl[(i >> 6) * 65 + (i & 63)] = w[i];
    for (int i = tid; i < 4096; i += 256) {
        float v = x[(size_t)(i >> 6) * THW_ + base + (i & 63)];
        xt[i] = v;
        ld[(i >> 6) * 65 + (i & 63)] = v;
    }
    if (tid < 256) wd[tid] = w_down[tid];
    __syncthreads();
    {
        int o_grp = tid >> 4, u_grp = tid & 15;
        float acc[4][4] = {};
        const float4* xt4 = (const float4*)xt;
        for (int c = 0; c < 64; ++c) {
            float xa[4];
            *(float4*)xa = xt4[c * 16 + u_grp];
            #pragma unroll
            for (int i = 0; i < 4; ++i) {
                float wv = wl[(o_grp * 4 + i) * 65 + c];
                #pragma unroll
                for (int g = 0; g < 4; ++g) acc[i][g] += wv * xa[g];
            }
        }
        #pragma unroll
        for (int g = 0; g < 4; ++g) {
            float4 v = make_float4(acc[0][g], acc[1][g], acc[2][g], acc[3][g]);
            *(float4*)&x2T[(size_t)(base + u_grp * 4 + g) * 64 + o_grp * 4] = v;
        }
    }
    {
        int r = tid >> 6, u = tid & 63;
        float a = 0.f;
        #pragma unroll 8
        for (int c = 0; c < 64; ++c) a += wd[r * 64 + c] * xt[c * 64 + u];
        xd[(size_t)r * THW_ + base + u] = a;
    }
    for (int i = tid; i < 4096; i += 256) {
        int u = i >> 6, c = i & 63;
        float v = ld[c * 65 + u];
        unsigned short h = f2bf(v);
        xbh[(size_t)(base + u) * 64 + c] = h;
        xbl[(size_t)(base + u) * 64 + c] = f2bf(v - bf2f(h));
    }
}

// ---------------- k_off (verbatim) ----------------
__global__ __launch_bounds__(256) void k_off(const float* __restrict__ x,
                                             const float* __restrict__ x2T,
                                             const float* __restrict__ w_l,
                                             const float* __restrict__ b_l,
                                             const float* __restrict__ w_r,
                                             const float* __restrict__ b_r,
                                             float* __restrict__ off) {
    __shared__ float wlds[2304];
    int tid = threadIdx.x;
    for (int i = tid; i < 2304; i += 256) wlds[i] = (i < 1152) ? w_l[i] : w_r[i - 1152];
    __syncthreads();
    int wg = blockIdx.x * 4 + (tid >> 6);
    int lane = tid & 63;
    int j = wg % 24, i = (wg / 24) % 24, t = (wg / 576) % 16, side = wg / 9216;
    int ts = (side == 0) ? min(t + 1, T_ - 1) : max(t - 1, 0);
    const float* wp = wlds + side * 1152;
    const float* xl = x + (size_t)lane * THW_ + t * HW_;
    const float* x2l = x2T + (size_t)ts * HW_ * 64 + lane;
    float a0 = 0.f, a1 = 0.f;
    for (int ki = 0; ki < 3; ++ki) {
        int hh = 2 * i - 1 + ki;
        if (hh < 0 || hh >= H_) continue;
        for (int kj = 0; kj < 3; ++kj) {
            int ww = 2 * j - 1 + kj;
            if (ww < 0 || ww >= W_) continue;
            int pos = hh * W_ + ww;
            float s = xl[pos] + x2l[(size_t)pos * 64];
            int tap = ki * 3 + kj;
            a0 += s * wp[lane * 9 + tap];
            a1 += s * wp[576 + lane * 9 + tap];
        }
    }
    #pragma unroll
    for (int m = 32; m >= 1; m >>= 1) {
        a0 += __shfl_xor(a0, m);
        a1 += __shfl_xor(a1, m);
    }
    if (lane == 0) {
        const float* bb = (side == 0) ? b_l : b_r;
        int ob = (side * 16 + t) * 1152 + i * 24 + j;
        off[ob] = a0 + bb[0];
        off[ob + 576] = a1 + bb[1];
    }
}

// ---------------- k_gs (verbatim) ----------------
__global__ __launch_bounds__(256) void k_gs(const float* __restrict__ x2T,
                                            const float* __restrict__ off,
                                            unsigned short* __restrict__ pch,
                                            unsigned short* __restrict__ pcl) {
    int wg = blockIdx.x * 4 + (threadIdx.x >> 6);
    int lane = threadIdx.x & 63;
    int sd = wg % 576;
    int t = (wg / 576) % 16;
    int side = wg / 9216;
    int d = sd % W2_, s = sd / W2_;
    const float* offp = off + (side * 16 + t) * 1152;
    float v0 = 2.f * (float)d + offp[sd];
    float v1 = 2.f * (float)s + offp[576 + sd];
    float xf = 48.f * v0 / 23.f - 0.5f;
    float yf = 48.f * v1 / 23.f - 0.5f;
    float x0 = floorf(xf), y0 = floorf(yf);
    int ix0 = (int)x0, iy0 = (int)y0;
    float fx = xf - x0, fy = yf - y0;
    float w00 = (1.f - fx) * (1.f - fy), w10 = fx * (1.f - fy);
    float w01 = (1.f - fx) * fy,         w11 = fx * fy;
    bool vx0 = (ix0 >= 0 && ix0 < W_), vx1 = (ix0 + 1 >= 0 && ix0 + 1 < W_);
    bool vy0 = (iy0 >= 0 && iy0 < H_), vy1 = (iy0 + 1 >= 0 && iy0 + 1 < H_);
    int cx0 = min(max(ix0, 0), W_ - 1), cx1 = min(max(ix0 + 1, 0), W_ - 1);
    int cy0 = min(max(iy0, 0), H_ - 1), cy1 = min(max(iy0 + 1, 0), H_ - 1);
    float m00 = (vx0 && vy0) ? w00 : 0.f;
    float m10 = (vx1 && vy0) ? w10 : 0.f;
    float m01 = (vx0 && vy1) ? w01 : 0.f;
    float m11 = (vx1 && vy1) ? w11 : 0.f;
    int ts = (side == 0) ? min(t + 1, T_ - 1) : max(t - 1, 0);
    const float* img = x2T + (size_t)ts * HW_ * 64;
    float val = m00 * img[(size_t)(cy0 * W_ + cx0) * 64 + lane]
              + m10 * img[(size_t)(cy0 * W_ + cx1) * 64 + lane]
              + m01 * img[(size_t)(cy1 * W_ + cx0) * 64 + lane]
              + m11 * img[(size_t)(cy1 * W_ + cx1) * 64 + lane];
    size_t idx = ((size_t)(side * 16 + t) * 576 + sd) * 64 + lane;
    unsigned short h = f2bf(val);
    pch[idx] = h;
    pcl[idx] = f2bf(val - bf2f(h));
}

// ---------------- k_tr (verbatim) ----------------
__global__ __launch_bounds__(256) void k_tr(const unsigned short* __restrict__ pch,
                                            unsigned short* __restrict__ partb) {
    int st = blockIdx.x / 9;
    int sdt = blockIdx.x % 9;
    __shared__ unsigned short ld[64 * 68];
    int tid = threadIdx.x;
    const unsigned short* src = pch + ((size_t)st * 576 + sdt * 64) * 64;
    for (int i = tid; i < 4096; i += 256) ld[(i >> 6) * 68 + (i & 63)] = src[i];
    __syncthreads();
    unsigned short* dst = partb + (size_t)st * 64 * 576 + sdt * 64;
    for (int i = tid; i < 4096; i += 256) {
        int c = i >> 6, sdl = i & 63;
        dst[(size_t)c * 576 + sdl] = ld[sdl * 68 + c];
    }
}

// ---------------- k_stats: LDS-staged + double-buffered prefetch, 1 barrier/iter -------
// grid: t(16) x hw-tile(36); 18 iterations = side(2) x kt(9)
__global__ __launch_bounds__(256) void k_stats(const unsigned short* __restrict__ xbh,
                                               const unsigned short* __restrict__ xbl,
                                               const unsigned short* __restrict__ pch,
                                               const unsigned short* __restrict__ pcl,
                                               float* __restrict__ stats) {
    int bid = blockIdx.x;
    int t = bid / 36, hwt = bid % 36;
    int base = t * HW_ + hwt * 64;
    __shared__ __attribute__((aligned(16))) unsigned short pah[2][64 * SDT_];
    __shared__ __attribute__((aligned(16))) unsigned short pal[2][64 * SDT_];
    int tid = threadIdx.x;
    int lane = tid & 63, wv = tid >> 6;
    int quad = lane >> 4, l15 = lane & 15;
    int m0 = wv * 16;
    // A-frags: per-wave-unique rows, direct from global (loaded once)
    const unsigned short* xrh = xbh + (size_t)(base + m0 + l15) * 64;
    const unsigned short* xrl = xbl + (size_t)(base + m0 + l15) * 64;
    short8 ah0 = *(const short8*)&xrh[quad * 8];
    short8 ah1 = *(const short8*)&xrh[32 + quad * 8];
    short8 al0 = *(const short8*)&xrl[quad * 8];
    short8 al1 = *(const short8*)&xrl[32 + quad * 8];
    int sH[4], sC[4];
    #pragma unroll
    for (int k = 0; k < 4; ++k) { int i = tid + k * 256; sH[k] = i >> 4; sC[k] = i & 15; }
    uint2 pf_h[4], pf_l[4];
    {   // prefetch idx 0
        const unsigned short* ph = pch + (size_t)t * 576 * 64;
        const unsigned short* pl = pcl + (size_t)t * 576 * 64;
        #pragma unroll
        for (int k = 0; k < 4; ++k) {
            pf_h[k] = *(const uint2*)&ph[(size_t)sH[k] * 64 + sC[k] * 4];
            pf_l[k] = *(const uint2*)&pl[(size_t)sH[k] * 64 + sC[k] * 4];
        }
    }
    float sum[2][4] = {}, sq[2][4] = {};
    float mx[2][4] = {{-1e30f,-1e30f,-1e30f,-1e30f},{-1e30f,-1e30f,-1e30f,-1e30f}};
    for (int idx = 0; idx < 18; ++idx) {
        int b = idx & 1;
        int side = idx / 9;
        #pragma unroll
        for (int k = 0; k < 4; ++k) {
            *(uint2*)&pah[b][sH[k] * SDT_ + sC[k] * 4] = pf_h[k];
            *(uint2*)&pal[b][sH[k] * SDT_ + sC[k] * 4] = pf_l[k];
        }
        if (idx < 17) {
            int nidx = idx + 1;
            int nside = nidx / 9, nkt = nidx % 9;
            const unsigned short* ph = pch + ((size_t)(nside * 16 + t) * 576 + nkt * 64) * 64;
            const unsigned short* pl = pcl + ((size_t)(nside * 16 + t) * 576 + nkt * 64) * 64;
            #pragma unroll
            for (int k = 0; k < 4; ++k) {
                pf_h[k] = *(const uint2*)&ph[(size_t)sH[k] * 64 + sC[k] * 4];
                pf_l[k] = *(const uint2*)&pl[(size_t)sH[k] * 64 + sC[k] * 4];
            }
        }
        __syncthreads();
        #pragma unroll
        for (int tile = 0; tile < 4; ++tile) {
            short8 bh0 = *(const short8*)&pah[b][(tile * 16 + l15) * SDT_ + quad * 8];
            short8 bh1 = *(const short8*)&pah[b][(tile * 16 + l15) * SDT_ + 32 + quad * 8];
            short8 bl0 = *(const short8*)&pal[b][(tile * 16 + l15) * SDT_ + quad * 8];
            short8 bl1 = *(const short8*)&pal[b][(tile * 16 + l15) * SDT_ + 32 + quad * 8];
            f32x4 dacc = {0.f, 0.f, 0.f, 0.f};
            dacc = __builtin_amdgcn_mfma_f32_16x16x32_bf16(ah0, bh0, dacc, 0, 0, 0);
            dacc = __builtin_amdgcn_mfma_f32_16x16x32_bf16(ah1, bh1, dacc, 0, 0, 0);
            dacc = __builtin_amdgcn_mfma_f32_16x16x32_bf16(ah0, bl0, dacc, 0, 0, 0);
            dacc = __builtin_amdgcn_mfma_f32_16x16x32_bf16(ah1, bl1, dacc, 0, 0, 0);
            dacc = __builtin_amdgcn_mfma_f32_16x16x32_bf16(al0, bh0, dacc, 0, 0, 0);
            dacc = __builtin_amdgcn_mfma_f32_16x16x32_bf16(al1, bh1, dacc, 0, 0, 0);
            #pragma unroll
            for (int r = 0; r < 4; ++r) {
                float v = dacc[r];
                sum[side][r] += v; sq[side][r] += v * v; mx[side][r] = fmaxf(mx[side][r], v);
            }
        }
    }
    #pragma unroll
    for (int side = 0; side < 2; ++side) {
        #pragma unroll
        for (int m = 1; m < 16; m <<= 1)
            #pragma unroll
            for (int r = 0; r < 4; ++r) {
                sum[side][r] += __shfl_xor(sum[side][r], m);
                sq[side][r]  += __shfl_xor(sq[side][r], m);
                mx[side][r]   = fmaxf(mx[side][r], __shfl_xor(mx[side][r], m));
            }
        if (l15 == 0) {
            #pragma unroll
            for (int r = 0; r < 4; ++r) {
                int thw = base + m0 + quad * 4 + r;
                stats[(side * 3 + 0) * THW_ + thw] = sum[side][r] * (1.f / 576.f);
                stats[(side * 3 + 1) * THW_ + thw] = mx[side][r];
                stats[(side * 3 + 2) * THW_ + thw] =
                    (sq[side][r] - sum[side][r] * sum[side][r] * (1.f / 576.f)) * (1.f / 575.f);
            }
        }
    }
}

// ---------------- k_attn (verbatim) ----------------
__global__ void k_attn(const float* __restrict__ stats, const float* __restrict__ ca_w1,
                       const float* __restrict__ ca_w2, float* __restrict__ yb) {
    int idx = blockIdx.x * 256 + threadIdx.x;
    if (idx >= 2 * THW_) return;
    int side = idx / THW_, thw = idx % THW_;
    int w = thw % W_, h = (thw / W_) % H_, t = thw / HW_;
    const float* avg = stats + (side * 3 + 0) * THW_ + t * HW_;
    const float* mxp = stats + (side * 3 + 1) * THW_ + t * HW_;
    const float* var = stats + (side * 3 + 2) * THW_ + t * HW_;
    float acc = 0.f;
    for (int ki = 0; ki < 3; ++ki) {
        int hh = h - 1 + ki;
        if (hh < 0 || hh >= H_) continue;
        for (int kj = 0; kj < 3; ++kj) {
            int ww = w - 1 + kj;
            if (ww < 0 || ww >= W_) continue;
            int p = hh * W_ + ww;
            int kk = ki * 3 + kj;
            acc += ca_w1[kk] * avg[p] + ca_w1[9 + kk] * mxp[p] + ca_w2[kk] * var[p];
        }
    }
    yb[idx] = sigm(acc);
}

// ---------------- k_agg (verbatim) ----------------
__global__ void k_agg(const float* __restrict__ xd,
                      const float* __restrict__ w1, const float* __restrict__ b1,
                      const float* __restrict__ w2, const float* __restrict__ b2,
                      const float* __restrict__ w3, const float* __restrict__ b3,
                      const float* __restrict__ wts, float* __restrict__ agg0) {
    int idx = blockIdx.x * 256 + threadIdx.x;
    if (idx >= RC_ * THW_) return;
    int w = idx % W_;
    int h = (idx / W_) % H_;
    int t = (idx / HW_) % T_;
    int r = idx / THW_;
    const float* xr = xd + r * THW_;
    const float* wk_arr[3] = {w1, w2, w3};
    const float* bs_arr[3] = {b1, b2, b3};
    float tot = 0.f;
    for (int m = 0; m < 3; ++m) {
        int dil = m + 1;
        float acc = bs_arr[m][r];
        const float* wk = wk_arr[m] + r * 81;
        for (int kt = 0; kt < 9; ++kt) {
            int tt = t - 4 + kt;
            if (tt < 0 || tt >= T_) continue;
            for (int kh = 0; kh < 3; ++kh) {
                int hh = h + (kh - 1) * dil;
                if (hh < 0 || hh >= H_) continue;
                for (int kw = 0; kw < 3; ++kw) {
                    int wwp = w + (kw - 1) * dil;
                    if (wwp < 0 || wwp >= W_) continue;
                    acc += xr[tt * HW_ + hh * W_ + wwp] * wk[kt * 9 + kh * 3 + kw];
                }
            }
        }
        tot += acc * wts[m];
    }
    agg0[idx] = tot;
}

// ---------------- k_final: staged + double-buffered prefetch, 2 barriers/iter ----------
// grid: t(16) x hw-tile(36); 18 iterations = side(2) x kt(9)
__global__ __launch_bounds__(256) void k_final(const unsigned short* __restrict__ xbh,
                                               const unsigned short* __restrict__ xbl,
                                               const unsigned short* __restrict__ pch,
                                               const unsigned short* __restrict__ pcl,
                                               const unsigned short* __restrict__ partb,
                                               const float* __restrict__ yb,
                                               const float* __restrict__ weights2,
                                               const float* __restrict__ agg0,
                                               const float* __restrict__ w_back,
                                               float* __restrict__ out) {
    int bid = blockIdx.x;
    int t = bid / 36, hwt = bid % 36;
    int base = t * HW_ + hwt * 64;
    __shared__ __attribute__((aligned(16))) unsigned short pah[2][64 * SDT_];
    __shared__ __attribute__((aligned(16))) unsigned short pal[2][64 * SDT_];
    __shared__ __attribute__((aligned(16))) unsigned short wt[64 * SDT_];
    int tid = threadIdx.x;
    int lane = tid & 63, wv = tid >> 6;
    int quad = lane >> 4, l15 = lane & 15;
    int m0 = wv * 16;
    const unsigned short* xrh = xbh + (size_t)(base + m0 + l15) * 64;
    const unsigned short* xrl = xbl + (size_t)(base + m0 + l15) * 64;
    short8 ah0 = *(const short8*)&xrh[quad * 8];
    short8 ah1 = *(const short8*)&xrh[32 + quad * 8];
    short8 al0 = *(const short8*)&xrl[quad * 8];
    short8 al1 = *(const short8*)&xrl[32 + quad * 8];
    float yv2[2][4];
    #pragma unroll
    for (int s = 0; s < 2; ++s)
        #pragma unroll
        for (int r = 0; r < 4; ++r) yv2[s][r] = yb[s * THW_ + base + m0 + quad * 4 + r];
    int sH[4], sC[4];
    #pragma unroll
    for (int k = 0; k < 4; ++k) { int i = tid + k * 256; sH[k] = i >> 4; sC[k] = i & 15; }
    uint2 pf_h[4], pf_l[4];
    short8 pbn0, pbn1;
    {   // prefetch idx 0 (side 0, kt 0)
        const unsigned short* ph = pch + (size_t)t * 576 * 64;
        const unsigned short* pl = pcl + (size_t)t * 576 * 64;
        #pragma unroll
        for (int k = 0; k < 4; ++k) {
            pf_h[k] = *(const uint2*)&ph[(size_t)sH[k] * 64 + sC[k] * 4];
            pf_l[k] = *(const uint2*)&pl[(size_t)sH[k] * 64 + sC[k] * 4];
        }
        const unsigned short* pbr = partb + (size_t)t * 64 * 576 + (size_t)(m0 + l15) * 576;
        pbn0 = *(const short8*)&pbr[quad * 8];
        pbn1 = *(const short8*)&pbr[32 + quad * 8];
    }
    f32x4 acc2[2][4] = {};
    for (int idx = 0; idx < 18; ++idx) {
        int b = idx & 1;
        int side = idx / 9;
        // write staged B-tiles from prefetch regs
        #pragma unroll
        for (int k = 0; k < 4; ++k) {
            *(uint2*)&pah[b][sH[k] * SDT_ + sC[k] * 4] = pf_h[k];
            *(uint2*)&pal[b][sH[k] * SDT_ + sC[k] * 4] = pf_l[k];
        }
        short8 pA0 = pbn0, pA1 = pbn1;
        if (idx < 17) {
            int nidx = idx + 1;
            int nside = nidx / 9, nkt = nidx % 9;
            const unsigned short* ph = pch + ((size_t)(nside * 16 + t) * 576 + nkt * 64) * 64;
            const unsigned short* pl = pcl + ((size_t)(nside * 16 + t) * 576 + nkt * 64) * 64;
            #pragma unroll
            for (int k = 0; k < 4; ++k) {
                pf_h[k] = *(const uint2*)&ph[(size_t)sH[k] * 64 + sC[k] * 4];
                pf_l[k] = *(const uint2*)&pl[(size_t)sH[k] * 64 + sC[k] * 4];
            }
            const unsigned short* pbr = partb + (size_t)(nside * 16 + t) * 64 * 576
                                      + (size_t)(m0 + l15) * 576 + nkt * 64;
            pbn0 = *(const short8*)&pbr[quad * 8];
            pbn1 = *(const short8*)&pbr[32 + quad * 8];
        }
        __syncthreads();   // staged tiles visible; prev phase B done reading wt
        // phase A: aff tiles -> sigmoid weights
        unsigned short wtv[4][4];
        #pragma unroll
        for (int tile = 0; tile < 4; ++tile) {
            short8 bh0 = *(const short8*)&pah[b][(tile * 16 + l15) * SDT_ + quad * 8];
            short8 bh1 = *(const short8*)&pah[b][(tile * 16 + l15) * SDT_ + 32 + quad * 8];
            short8 bl0 = *(const short8*)&pal[b][(tile * 16 + l15) * SDT_ + quad * 8];
            short8 bl1 = *(const short8*)&pal[b][(tile * 16 + l15) * SDT_ + 32 + quad * 8];
            f32x4 dacc = {0.f, 0.f, 0.f, 0.f};
            dacc = __builtin_amdgcn_mfma_f32_16x16x32_bf16(ah0, bh0, dacc, 0, 0, 0);
            dacc = __builtin_amdgcn_mfma_f32_16x16x32_bf16(ah1, bh1, dacc, 0, 0, 0);
            dacc = __builtin_amdgcn_mfma_f32_16x16x32_bf16(ah0, bl0, dacc, 0, 0, 0);
            dacc = __builtin_amdgcn_mfma_f32_16x16x32_bf16(ah1, bl1, dacc, 0, 0, 0);
            dacc = __builtin_amdgcn_mfma_f32_16x16x32_bf16(al0, bh0, dacc, 0, 0, 0);
            dacc = __builtin_amdgcn_mfma_f32_16x16x32_bf16(al1, bh1, dacc, 0, 0, 0);
            #pragma unroll
            for (int r = 0; r < 4; ++r)
                wtv[tile][r] = f2bf(sigm(dacc[r] * yv2[side][r]) - 0.5f);
        }
        #pragma unroll
        for (int tile = 0; tile < 4; ++tile)
            #pragma unroll
            for (int r = 0; r < 4; ++r)
                wt[(m0 + quad * 4 + r) * SDT_ + tile * 16 + l15] = wtv[tile][r];
        __syncthreads();   // wt visible
        // phase B: P (prefetched A-frag) x wt^T
        #pragma unroll
        for (int tile = 0; tile < 4; ++tile) {
            short8 wb0 = *(const short8*)&wt[(tile * 16 + l15) * SDT_ + quad * 8];
            short8 wb1 = *(const short8*)&wt[(tile * 16 + l15) * SDT_ + 32 + quad * 8];
            acc2[side][tile] = __builtin_amdgcn_mfma_f32_16x16x32_bf16(pA0, wb0, acc2[side][tile], 0, 0, 0);
            acc2[side][tile] = __builtin_amdgcn_mfma_f32_16x16x32_bf16(pA1, wb1, acc2[side][tile], 0, 0, 0);
        }
    }
    float w20 = weights2[0], w21 = weights2[1];
    #pragma unroll
    for (int tile = 0; tile < 4; ++tile) {
        int thw = base + tile * 16 + l15;
        #pragma unroll
        for (int r = 0; r < 4; ++r) {
            int c = m0 + quad * 4 + r;
            float a = 0.f;
            #pragma unroll
            for (int rr = 0; rr < RC_; ++rr) a += w_back[c * RC_ + rr] * agg0[rr * THW_ + thw];
            out[(size_t)c * THW_ + thw] =
                (acc2[0][tile][r] * w20 + acc2[1][tile][r] * w21) * (sigm(a) - 0.5f);
        }
    }
}

extern "C" void kernel_launch(void* const* d_in, const int* in_sizes, int n_in,
                              void* d_out, int out_size, void* d_ws, size_t ws_size,
                              hipStream_t stream) {
    const float* x       = (const float*)d_in[0];
    const float* w_dc2   = (const float*)d_in[1];
    const float* w_ofs_l = (const float*)d_in[2];
    const float* b_ofs_l = (const float*)d_in[3];
    const float* w_ofs_r = (const float*)d_in[4];
    const float* b_ofs_r = (const float*)d_in[5];
    const float* ca_w1   = (const float*)d_in[6];
    const float* ca_w2   = (const float*)d_in[7];
    const float* w_down  = (const float*)d_in[8];
    const float* sa1_w   = (const float*)d_in[9];
    const float* sa1_b   = (const float*)d_in[10];
    const float* sa2_w   = (const float*)d_in[11];
    const float* sa2_b   = (const float*)d_in[12];
    const float* sa3_w   = (const float*)d_in[13];
    const float* sa3_b   = (const float*)d_in[14];
    const float* weights = (const float*)d_in[15];
    const float* weights2= (const float*)d_in[16];
    const float* w_back  = (const float*)d_in[17];
    float* out = (float*)d_out;

    // workspace ~24.3 MB (identical layout to rounds 11/12)
    float* ws    = (float*)d_ws;
    float* x2T   = ws;                               // CTHW_ f32
    float* stats = x2T;                              // overlay: 221,184 f32
    float* yb    = stats + 2 * 3 * THW_;             // 73,728
    float* agg0  = yb + 2 * THW_;                    // 147,456
    unsigned short* partb = (unsigned short*)(agg0 + RC_ * THW_);  // 1,179,648 u16
    float* off   = ws + CTHW_;                       // 36,864 f32
    unsigned short* xbh = (unsigned short*)(off + 2 * T_ * 2 * SD_);  // CTHW_ u16
    unsigned short* xbl = xbh + CTHW_;                                // CTHW_ u16
    unsigned short* pch = xbl + CTHW_;               // 1,179,648 u16
    unsigned short* pcl = pch + 2 * 16 * 576 * 64;   // 1,179,648 u16
    float* xd    = (float*)(pcl + 2 * 16 * 576 * 64); // 147,456 f32

    k_pre<<<THW_ / 64, 256, 0, stream>>>(x, w_dc2, w_down, x2T, xbh, xbl, xd);
    k_off<<<(2 * 16 * 576) / 4, 256, 0, stream>>>(x, x2T, w_ofs_l, b_ofs_l,
                                                  w_ofs_r, b_ofs_r, off);
    k_gs<<<(2 * 16 * 576) / 4, 256, 0, stream>>>(x2T, off, pch, pcl);
    k_tr<<<32 * 9, 256, 0, stream>>>(pch, partb);
    k_stats<<<16 * 36, 256, 0, stream>>>(xbh, xbl, pch, pcl, stats);
    k_attn<<<(2 * THW_) / 256, 256, 0, stream>>>(stats, ca_w1, ca_w2, yb);
    k_agg<<<(RC_ * THW_) / 256, 256, 0, stream>>>(xd, sa1_w, sa1_b, sa2_w, sa2_b,
                                                  sa3_w, sa3_b, weights, agg0);
    k_final<<<16 * 36, 256, 0, stream>>>(xbh, xbl, pch, pcl, partb, yb, weights2,
                                         agg0, w_back, out);
}